// Round 13
// baseline (432.127 us; speedup 1.0000x reference)
//
#include <hip/hip_runtime.h>
#include <hip/hip_cooperative_groups.h>

namespace cg = cooperative_groups;

// H=16, DK=DV=64, D=1024, N=M=2048.
// scores[h,n,m] = ((A_h^T q_n + vh_h) . k_m)/8 + row-consts (drop in softmax),
//   A_h[i][j] = sum_d Wq[h,i,d]*Wk[h,j,d],  vh_h[j] = sum_d Wk[h,j,d]*bq[h,d].
// r_h[v] = sum_m g_h[m]*values[m,v],  g_h[m] = sum_n exp(s[n,m])/l[n],
// l[n] = sum_m exp(s[n,m]).  pooled = r.Wv + 2048*sum_h bv; out = pooled.Wo^T+bo.
// No max-tracking: |s|max ~ 27 << 88 -> exp2 safe in fp32.
//
// v13 = v12's six kernels fused into ONE cooperative kernel (512 blocks x 256
// thr, 2 blocks/CU co-resident) with grid.sync() between phases. Phase bodies
// are byte-identical v12; the ONLY variable is orchestration. Rationale:
// v12's budget = fill ~43us (harness, fixed) + kernels ~65us + ~26us of
// inter-kernel launch/drain gaps (6 dispatches) -- the gaps are now the
// largest controllable line-item. grid.sync() provides the cross-phase
// ordering + device-scope visibility (guide G16's sanctioned route).

typedef __attribute__((ext_vector_type(4))) float floatx4;
typedef __attribute__((ext_vector_type(8))) short shortx8;

__device__ inline unsigned short f2bf(float f) {
    unsigned int u = __float_as_uint(f);
    u += 0x7FFFu + ((u >> 16) & 1u);   // RNE
    return (unsigned short)(u >> 16);
}
__device__ inline float bf2f(unsigned short s) {
    return __uint_as_float(((unsigned int)s) << 16);
}

#define SWZ(row, bc) ((row) * 128 + ((bc) ^ (((row) & 7) << 4)))
#define QSCALE 0.18033688f   /* 0.125 * log2(e) */

__global__ __launch_bounds__(256, 2) void fused_kernel(
    const float* __restrict__ Wq, const float* __restrict__ Wk,
    const float* __restrict__ bq, const float* __restrict__ keys,
    const float* __restrict__ values, const float* __restrict__ queries,
    const float* __restrict__ Wv, const float* __restrict__ bv,
    const float* __restrict__ Wo, const float* __restrict__ bo,
    float* __restrict__ Apart, float* __restrict__ vhpart,
    unsigned short* __restrict__ Kb, unsigned short* __restrict__ Atlg,
    float* __restrict__ vhg, unsigned short* __restrict__ Qhs,
    float* __restrict__ u_ws, float* __restrict__ r_ws,
    float* __restrict__ pooled, float* __restrict__ out) {
    cg::grid_group grid = cg::this_grid();
    const int tid = threadIdx.x;
    const int bx = blockIdx.x;
    __shared__ __align__(16) unsigned char sm[36608];

    // ================= P0: prep (blocks 0-143) ==============================
    if (bx < 128) {
        const int g = bx >> 4, h = bx & 15;
        const int c0 = g * 128;
        unsigned short* wq = (unsigned short*)sm;            // 64*136 ushort
        unsigned short* wk = (unsigned short*)(sm + 17408);  // 64*136 ushort
        float* bqs = (float*)(sm + 34816);                   // 128
        float* vred = (float*)(sm + 35328);                  // 4*64
        {
            int row = tid >> 2, cs = (tid & 3) * 32;
            const float* wqp = Wq + (size_t)(h * 64 + row) * 1024 + c0 + cs;
            const float* wkp = Wk + (size_t)(h * 64 + row) * 1024 + c0 + cs;
            #pragma unroll
            for (int u = 0; u < 8; ++u) {
                float4 a = *(const float4*)&wqp[u * 4];
                float4 b = *(const float4*)&wkp[u * 4];
                *(ushort4*)&wq[row * 136 + cs + u * 4] =
                    (ushort4){f2bf(a.x), f2bf(a.y), f2bf(a.z), f2bf(a.w)};
                *(ushort4*)&wk[row * 136 + cs + u * 4] =
                    (ushort4){f2bf(b.x), f2bf(b.y), f2bf(b.z), f2bf(b.w)};
            }
            if (tid < 128) bqs[tid] = bq[h * 1024 + c0 + tid];
        }
        __syncthreads();
        const int w = tid >> 6, lane = tid & 63;
        const int ln = lane & 15, quad = lane >> 4;
        {   // vh partial
            const int j = tid & 63, half = tid >> 6;
            float accv = 0.f;
            #pragma unroll
            for (int u = 0; u < 32; ++u)
                accv += bf2f(wk[j * 136 + half * 32 + u]) * bqs[half * 32 + u];
            vred[half * 64 + j] = accv;
        }
        shortx8 af[4];
        #pragma unroll
        for (int kk = 0; kk < 4; ++kk)
            af[kk] = *(shortx8*)&wq[(w * 16 + ln) * 136 + kk * 32 + quad * 8];
        float* ap = Apart + (size_t)bx * 4096;
        #pragma unroll
        for (int cn = 0; cn < 4; ++cn) {
            floatx4 acc = {};
            #pragma unroll
            for (int kk = 0; kk < 4; ++kk) {
                shortx8 bf_ = *(shortx8*)&wk[(cn * 16 + ln) * 136 + kk * 32 + quad * 8];
                acc = __builtin_amdgcn_mfma_f32_16x16x32_bf16(af[kk], bf_, acc, 0, 0, 0);
            }
            #pragma unroll
            for (int r = 0; r < 4; ++r)
                ap[(w * 16 + quad * 4 + r) * 64 + cn * 16 + ln] = acc[r];
        }
        __syncthreads();
        if (tid < 64)
            vhpart[bx * 64 + tid] = vred[tid] + vred[64 + tid] +
                                    vred[128 + tid] + vred[192 + tid];
    } else if (bx < 144) {
        int bk = bx - 128;
        int base = (bk * 256 + tid) * 32;
        #pragma unroll
        for (int u = 0; u < 8; ++u) {
            float4 a = *(const float4*)&keys[base + u * 4];
            *(ushort4*)&Kb[base + u * 4] =
                (ushort4){f2bf(a.x), f2bf(a.y), f2bf(a.z), f2bf(a.w)};
        }
        if (tid < 64) r_ws[bk * 64 + tid] = 0.f;
    }
    grid.sync();

    // ================= P1: reduceA (blocks 0-63) ============================
    if (bx < 64) {
        const int h = bx >> 2, uq = bx & 3;
        #pragma unroll
        for (int uu = 0; uu < 4; ++uu) {
            int e = (uq * 4 + uu) * 256 + tid;     // e = i*64 + j
            float s = 0.f;
            #pragma unroll
            for (int g = 0; g < 8; ++g)
                s += Apart[g * 65536 + h * 4096 + e];
            Atlg[h * 4096 + (e & 63) * 64 + (e >> 6)] = f2bf(s);   // A^T[j][i]
        }
        if (uq == 0 && tid < 64) {
            float s = 0.f;
            #pragma unroll
            for (int g = 0; g < 8; ++g) s += vhpart[(g * 16 + h) * 64 + tid];
            vhg[h * 64 + tid] = s;
        }
    }
    grid.sync();

    // ================= P2: pass1 (all 512 blocks) ===========================
    {
        const int h = bx >> 5;
        const int n0 = (bx & 31) * 64;
        const int w = tid >> 6, lane = tid & 63;
        const int ln = lane & 15, quad = lane >> 4;
        unsigned short* qstage = (unsigned short*)sm;
        unsigned short* Atl = (unsigned short*)(sm + 9216);
        unsigned short* qh = (unsigned short*)(sm + 24576);
        float* vhs = (float*)(sm + 33792);

        {
            int row = tid >> 2, c16 = (tid & 3) * 16;
            const float* qp = queries + (size_t)(n0 + row) * 64 + c16;
            #pragma unroll
            for (int u = 0; u < 4; ++u) {
                float4 a = *(const float4*)&qp[u * 4];
                *(ushort4*)&qstage[row * 72 + c16 + u * 4] =
                    (ushort4){f2bf(a.x), f2bf(a.y), f2bf(a.z), f2bf(a.w)};
            }
            #pragma unroll
            for (int u = 0; u < 2; ++u)
                *(shortx8*)&Atl[row * 72 + c16 + u * 8] =
                    *(const shortx8*)&Atlg[h * 4096 + row * 64 + c16 + u * 8];
        }
        if (tid < 64) vhs[tid] = vhg[h * 64 + tid];
        __syncthreads();

        {
            shortx8 qa[2];
            #pragma unroll
            for (int kk = 0; kk < 2; ++kk)
                qa[kk] = *(shortx8*)&qstage[(w * 16 + ln) * 72 + kk * 32 + quad * 8];
            #pragma unroll
            for (int cn = 0; cn < 4; ++cn) {
                floatx4 acc = {};
                #pragma unroll
                for (int kk = 0; kk < 2; ++kk) {
                    shortx8 bfr = *(shortx8*)&Atl[(cn * 16 + ln) * 72 + kk * 32 + quad * 8];
                    acc = __builtin_amdgcn_mfma_f32_16x16x32_bf16(qa[kk], bfr, acc, 0, 0, 0);
                }
                #pragma unroll
                for (int r = 0; r < 4; ++r)
                    qh[(w * 16 + quad * 4 + r) * 72 + cn * 16 + ln] =
                        f2bf((acc[r] + vhs[cn * 16 + ln]) * QSCALE);
            }
        }
        __syncthreads();   // qh published; qstage/Atl dead

        #pragma unroll
        for (int k = 0; k < 2; ++k) {
            int seg = tid * 2 + k, row = seg >> 3, off = (seg & 7) * 8;
            *(shortx8*)&Qhs[((size_t)h * 2048 + n0 + row) * 64 + off] =
                *(shortx8*)&qh[row * 72 + off];
        }
        const int srow = tid >> 2, sc = (tid & 3) * 16;
        #pragma unroll
        for (int i = 0; i < 2; ++i)
            *(shortx8*)(sm + SWZ(srow, sc * 2 + i * 16)) =
                *(const shortx8*)&Kb[(size_t)srow * 64 + sc + i * 8];
        shortx8 kr[2];
        #pragma unroll
        for (int i = 0; i < 2; ++i)
            kr[i] = *(const shortx8*)&Kb[(size_t)(64 + srow) * 64 + sc + i * 8];
        shortx8 qf[2];
        #pragma unroll
        for (int kk = 0; kk < 2; ++kk)
            qf[kk] = *(shortx8*)&qh[(w * 16 + ln) * 72 + kk * 32 + quad * 8];
        __syncthreads();

        float lacc[4] = {};
        int rb = 0;
        for (int s = 0; s < 32; ++s) {
            const unsigned char* kb = sm + rb * 8192;
            const int wb = (rb == 2) ? 0 : rb + 1;
            if (s < 31) {
                #pragma unroll
                for (int i = 0; i < 2; ++i)
                    *(shortx8*)(sm + wb * 8192 + SWZ(srow, sc * 2 + i * 16)) = kr[i];
            }
            if (s < 30) {
                int m0n = (s + 2) * 64;
                #pragma unroll
                for (int i = 0; i < 2; ++i)
                    kr[i] = *(const shortx8*)&Kb[(size_t)(m0n + srow) * 64 + sc + i * 8];
            }
            #pragma unroll
            for (int cm = 0; cm < 4; ++cm) {
                shortx8 kf0 = *(const shortx8*)(kb + SWZ(cm * 16 + ln, quad * 16));
                shortx8 kf1 = *(const shortx8*)(kb + SWZ(cm * 16 + ln, 64 + quad * 16));
                floatx4 acc = {};
                acc = __builtin_amdgcn_mfma_f32_16x16x32_bf16(qf[0], kf0, acc, 0, 0, 0);
                acc = __builtin_amdgcn_mfma_f32_16x16x32_bf16(qf[1], kf1, acc, 0, 0, 0);
                #pragma unroll
                for (int r = 0; r < 4; ++r)
                    lacc[r] += __builtin_amdgcn_exp2f(acc[r]);
            }
            __syncthreads();
            rb = wb;
        }
        #pragma unroll
        for (int r = 0; r < 4; ++r) {
            float x = lacc[r];
            #pragma unroll
            for (int o = 1; o <= 8; o <<= 1) x += __shfl_xor(x, o);
            if (ln == 0)
                u_ws[(size_t)h * 2048 + n0 + w * 16 + quad * 4 + r] = 1.0f / x;
        }
    }
    grid.sync();

    // ================= P3: pass2 (all 512 blocks) ===========================
    {
        const int h = bx >> 5;
        const int mb = (bx & 31) * 64;
        const int w = tid >> 6, lane = tid & 63;
        const int ln = lane & 15, quad = lane >> 4;
        float* u_sb = (float*)(sm + 24576);
        float* g_s = (float*)(sm + 25344);
        float* Rred = (float*)(sm + 25600);

        shortx8 kf[2];
        #pragma unroll
        for (int kk = 0; kk < 2; ++kk)
            kf[kk] = *(const shortx8*)&Kb[(size_t)(mb + w * 16 + ln) * 64 + kk * 32 + quad * 8];

        const int srow = tid >> 2, sc = (tid & 3) * 16;
        #pragma unroll
        for (int i = 0; i < 2; ++i)
            *(shortx8*)(sm + SWZ(srow, sc * 2 + i * 16)) =
                *(const shortx8*)&Qhs[((size_t)h * 2048 + srow) * 64 + sc + i * 8];
        if (tid < 64) u_sb[tid] = u_ws[(size_t)h * 2048 + tid];
        shortx8 qrn[2];
        float urn = 0.f;
        #pragma unroll
        for (int i = 0; i < 2; ++i)
            qrn[i] = *(const shortx8*)&Qhs[((size_t)h * 2048 + 64 + srow) * 64 + sc + i * 8];
        if (tid < 64) urn = u_ws[(size_t)h * 2048 + 64 + tid];
        __syncthreads();

        float gacc = 0.f;
        int rb = 0;
        for (int s = 0; s < 32; ++s) {
            const unsigned char* qb = sm + rb * 8192;
            const float* us = u_sb + rb * 64;
            const int wb = (rb == 2) ? 0 : rb + 1;
            if (s < 31) {
                #pragma unroll
                for (int i = 0; i < 2; ++i)
                    *(shortx8*)(sm + wb * 8192 + SWZ(srow, sc * 2 + i * 16)) = qrn[i];
                if (tid < 64) u_sb[wb * 64 + tid] = urn;
            }
            if (s < 30) {
                int n0n = (s + 2) * 64;
                #pragma unroll
                for (int i = 0; i < 2; ++i)
                    qrn[i] = *(const shortx8*)&Qhs[((size_t)h * 2048 + n0n + srow) * 64 + sc + i * 8];
                if (tid < 64) urn = u_ws[(size_t)h * 2048 + n0n + tid];
            }
            #pragma unroll
            for (int rt = 0; rt < 4; ++rt) {
                shortx8 qa0 = *(const shortx8*)(qb + SWZ(rt * 16 + ln, quad * 16));
                shortx8 qa1 = *(const shortx8*)(qb + SWZ(rt * 16 + ln, 64 + quad * 16));
                floatx4 acc = {};
                acc = __builtin_amdgcn_mfma_f32_16x16x32_bf16(qa0, kf[0], acc, 0, 0, 0);
                acc = __builtin_amdgcn_mfma_f32_16x16x32_bf16(qa1, kf[1], acc, 0, 0, 0);
                #pragma unroll
                for (int r = 0; r < 4; ++r)
                    gacc += __builtin_amdgcn_exp2f(acc[r]) * us[rt * 16 + quad * 4 + r];
            }
            __syncthreads();
            rb = wb;
        }

        gacc += __shfl_xor(gacc, 16);
        gacc += __shfl_xor(gacc, 32);
        if (quad == 0) g_s[w * 16 + ln] = gacc;   // column m = mb + w*16 + ln
        __syncthreads();
        {
            int grp = tid >> 6, v = tid & 63;
            float acc = 0.f;
            #pragma unroll
            for (int j = 0; j < 16; ++j)
                acc += g_s[grp * 16 + j] *
                       values[(size_t)(mb + grp * 16 + j) * 64 + v];
            Rred[grp * 64 + v] = acc;
        }
        __syncthreads();
        if (tid < 64)
            atomicAdd(&r_ws[h * 64 + tid],
                      Rred[tid] + Rred[64 + tid] + Rred[128 + tid] + Rred[192 + tid]);
    }
    grid.sync();

    // ================= P4: pool (blocks 0-63) ===============================
    if (bx < 64) {
        const int d0 = bx * 16;
        const int d = tid & 15, hh = tid >> 4;
        float* red = (float*)sm;   // [16][17]
        float acc = bv[hh * 1024 + d0 + d] * 2048.0f;
        const float* rv = r_ws + hh * 64;
        const float* wp = Wv + (size_t)hh * 64 * 1024 + d0 + d;
        #pragma unroll 8
        for (int v = 0; v < 64; ++v) acc += rv[v] * wp[(size_t)v * 1024];
        red[hh * 17 + d] = acc;
        __syncthreads();
        if (tid < 16) {
            float s = 0.f;
            #pragma unroll
            for (int g = 0; g < 16; ++g) s += red[g * 17 + tid];
            pooled[d0 + tid] = s;
        }
    }
    grid.sync();

    // ================= P5: out (blocks 0-255) ===============================
    if (bx < 256) {
        const int w = tid >> 6, lane = tid & 63;
        const int dp = bx * 4 + w;
        const float* wr = Wo + (size_t)dp * 1024 + lane * 16;
        const float* pp = pooled + lane * 16;
        float acc = 0.f;
        #pragma unroll
        for (int u = 0; u < 4; ++u) {
            float4 a = *(const float4*)&wr[u * 4];
            float4 p = *(const float4*)&pp[u * 4];
            acc += a.x * p.x + a.y * p.y + a.z * p.z + a.w * p.w;
        }
        #pragma unroll
        for (int o = 32; o > 0; o >>= 1) acc += __shfl_xor(acc, o);
        if (lane == 0) out[dp] = acc + bo[dp];
    }
}

extern "C" void kernel_launch(void* const* d_in, const int* in_sizes, int n_in,
                              void* d_out, int out_size, void* d_ws, size_t ws_size,
                              hipStream_t stream) {
    const float* queries = (const float*)d_in[0];
    const float* keys    = (const float*)d_in[1];
    const float* values  = (const float*)d_in[2];
    const float* Wq      = (const float*)d_in[3];
    const float* bq      = (const float*)d_in[4];
    const float* Wk      = (const float*)d_in[5];
    // d_in[6] = bk: row-constant under softmax, unused
    const float* Wv      = (const float*)d_in[7];
    const float* bv      = (const float*)d_in[8];
    const float* Wo      = (const float*)d_in[9];
    const float* bo      = (const float*)d_in[10];
    float* out = (float*)d_out;

    // workspace layout (bytes). Qhs (4MB) overlays Apart+vhpart: Apart/vhpart
    // are dead after P1, and P2 (which writes Qhs) runs after grid.sync.
    char* base = (char*)d_ws;
    unsigned short* Qhs = (unsigned short*)base;             // 16*2048*64 bf16 = 4MB
    float* Apart  = (float*)base;                            // 128*4096 f (overlay)
    float* vhpart = Apart + 524288;                          // 128*64 f (overlay)
    float* u_ws   = (float*)(base + 4194304);                // 16*2048 f
    float* r_ws   = (float*)(base + 4325376);                // 1024 f
    float* pooled = (float*)(base + 4329472);                // 1024 f
    unsigned short* Kb   = (unsigned short*)(base + 4333568);  // 2048*64 bf16
    unsigned short* Atlg = (unsigned short*)(base + 4595712);  // 16*64*64 bf16
    float* vhg    = (float*)(base + 4726784);                // 16*64 f
    // total ws: ~4.52 MB

    void* args[] = {
        (void*)&Wq, (void*)&Wk, (void*)&bq, (void*)&keys, (void*)&values,
        (void*)&queries, (void*)&Wv, (void*)&bv, (void*)&Wo, (void*)&bo,
        (void*)&Apart, (void*)&vhpart, (void*)&Kb, (void*)&Atlg, (void*)&vhg,
        (void*)&Qhs, (void*)&u_ws, (void*)&r_ws, (void*)&pooled, (void*)&out};
    hipLaunchCooperativeKernel((void*)fused_kernel, dim3(512), dim3(256),
                               args, 0, stream);
}

// Round 14
// 171.856 us; speedup vs baseline: 2.5145x; 2.5145x over previous
//
#include <hip/hip_runtime.h>

// H=16, DK=DV=64, D=1024, N=M=2048.
// scores[h,n,m] = ((A_h^T q_n + vh_h) . k_m)/8 + row-consts (drop in softmax),
//   A_h[i][j] = sum_d Wq[h,i,d]*Wk[h,j,d],  vh_h[j] = sum_d Wk[h,j,d]*bq[h,d].
// r_h[v] = sum_m g_h[m]*values[m,v],  g_h[m] = sum_n exp(s[n,m])/l[n],
// l[n] = sum_m exp(s[n,m]).  pooled = r.Wv + 2048*sum_h bv; out = pooled.Wo^T+bo.
// No max-tracking: |s|max ~ 27 << 88 -> exp2 safe in fp32.
//
// v14 = v12 + ONE conceptual change: passes re-tiled to 4 blocks/CU.
// v12's passes were grid-capped at 2 blocks/CU (2 waves/SIMD) with ~500cy
// serial steps -> latency exposed. Now: pass1 = 64 n-tiles of 32 rows
// (grid (64,16)=1024), waves split (row-tile, key-half); pass2 = 64 m-tiles
// of 32 cols, waves split (col-tile, row-half); partials combined in LDS at
// block end. No divergent block roles, no new atomics (v10's failure mode).
// Staging (3-deep + SWZ), prep, reduceA, pool, out byte-identical v12.
// (v13 lesson: grid.sync() costs ~54us on MI355X -- cooperative fusion dead.)

typedef __attribute__((ext_vector_type(4))) float floatx4;
typedef __attribute__((ext_vector_type(8))) short shortx8;

__device__ inline unsigned short f2bf(float f) {
    unsigned int u = __float_as_uint(f);
    u += 0x7FFFu + ((u >> 16) & 1u);   // RNE
    return (unsigned short)(u >> 16);
}
__device__ inline float bf2f(unsigned short s) {
    return __uint_as_float(((unsigned int)s) << 16);
}

#define SWZ(row, bc) ((row) * 128 + ((bc) ^ (((row) & 7) << 4)))
#define QSCALE 0.18033688f   /* 0.125 * log2(e) */

// =================== prep: fused A-partials / K-cvt =========================
// grid 144: blocks 0-127: (g,h) A-partial + vh-partial via MFMA (k-chunk 128)
//           blocks 128-143: K bf16 convert (linear) + r zero
__global__ __launch_bounds__(256) void prep_kernel(
    const float* __restrict__ Wq, const float* __restrict__ Wk,
    const float* __restrict__ bq, const float* __restrict__ keys,
    float* __restrict__ Apart, float* __restrict__ vhpart,
    unsigned short* __restrict__ Kb, float* __restrict__ r_ws) {
    const int tid = threadIdx.x;
    const int bx = blockIdx.x;
    __shared__ __align__(16) unsigned char sm[36352];
    if (bx < 128) {
        const int g = bx >> 4, h = bx & 15;
        const int c0 = g * 128;
        unsigned short* wq = (unsigned short*)sm;            // 64*136 ushort
        unsigned short* wk = (unsigned short*)(sm + 17408);  // 64*136 ushort
        float* bqs = (float*)(sm + 34816);                   // 128
        float* vred = (float*)(sm + 35328);                  // 4*64
        {
            int row = tid >> 2, cs = (tid & 3) * 32;
            const float* wqp = Wq + (size_t)(h * 64 + row) * 1024 + c0 + cs;
            const float* wkp = Wk + (size_t)(h * 64 + row) * 1024 + c0 + cs;
            #pragma unroll
            for (int u = 0; u < 8; ++u) {
                float4 a = *(const float4*)&wqp[u * 4];
                float4 b = *(const float4*)&wkp[u * 4];
                *(ushort4*)&wq[row * 136 + cs + u * 4] =
                    (ushort4){f2bf(a.x), f2bf(a.y), f2bf(a.z), f2bf(a.w)};
                *(ushort4*)&wk[row * 136 + cs + u * 4] =
                    (ushort4){f2bf(b.x), f2bf(b.y), f2bf(b.z), f2bf(b.w)};
            }
            if (tid < 128) bqs[tid] = bq[h * 1024 + c0 + tid];
        }
        __syncthreads();
        const int w = tid >> 6, lane = tid & 63;
        const int ln = lane & 15, quad = lane >> 4;
        {   // vh partial
            const int j = tid & 63, half = tid >> 6;
            float accv = 0.f;
            #pragma unroll
            for (int u = 0; u < 32; ++u)
                accv += bf2f(wk[j * 136 + half * 32 + u]) * bqs[half * 32 + u];
            vred[half * 64 + j] = accv;
        }
        // A-tile: wave w -> rows w*16..+15
        shortx8 af[4];
        #pragma unroll
        for (int kk = 0; kk < 4; ++kk)
            af[kk] = *(shortx8*)&wq[(w * 16 + ln) * 136 + kk * 32 + quad * 8];
        float* ap = Apart + (size_t)bx * 4096;
        #pragma unroll
        for (int cn = 0; cn < 4; ++cn) {
            floatx4 acc = {};
            #pragma unroll
            for (int kk = 0; kk < 4; ++kk) {
                shortx8 bf_ = *(shortx8*)&wk[(cn * 16 + ln) * 136 + kk * 32 + quad * 8];
                acc = __builtin_amdgcn_mfma_f32_16x16x32_bf16(af[kk], bf_, acc, 0, 0, 0);
            }
            #pragma unroll
            for (int r = 0; r < 4; ++r)
                ap[(w * 16 + quad * 4 + r) * 64 + cn * 16 + ln] = acc[r];
        }
        __syncthreads();
        if (tid < 64)
            vhpart[bx * 64 + tid] = vred[tid] + vred[64 + tid] +
                                    vred[128 + tid] + vred[192 + tid];
    } else {
        int bk = bx - 128;
        int base = (bk * 256 + tid) * 32;
        #pragma unroll
        for (int u = 0; u < 8; ++u) {
            float4 a = *(const float4*)&keys[base + u * 4];
            *(ushort4*)&Kb[base + u * 4] =
                (ushort4){f2bf(a.x), f2bf(a.y), f2bf(a.z), f2bf(a.w)};
        }
        if (tid < 64) r_ws[bk * 64 + tid] = 0.f;
    }
}

// =================== reduceA: sum 8 A-partials -> Atlg (A^T, bf16), vhg ======
__global__ __launch_bounds__(256) void reduceA_kernel(
    const float* __restrict__ Apart, const float* __restrict__ vhpart,
    unsigned short* __restrict__ Atlg, float* __restrict__ vhg) {
    const int tid = threadIdx.x;
    const int h = blockIdx.x >> 2, uq = blockIdx.x & 3;
    #pragma unroll
    for (int uu = 0; uu < 4; ++uu) {
        int e = (uq * 4 + uu) * 256 + tid;     // e = i*64 + j
        float s = 0.f;
        #pragma unroll
        for (int g = 0; g < 8; ++g)
            s += Apart[g * 65536 + h * 4096 + e];
        Atlg[h * 4096 + (e & 63) * 64 + (e >> 6)] = f2bf(s);   // A^T[j][i]
    }
    if (uq == 0 && tid < 64) {
        float s = 0.f;
        #pragma unroll
        for (int g = 0; g < 8; ++g) s += vhpart[(g * 16 + h) * 64 + tid];
        vhg[h * 64 + tid] = s;
    }
}

// =================== pass1: u[h,n] = 1/sum_m exp2(qhat.k) ====================
// grid (64 ntiles of 32 rows, 16 h) = 1024 blocks (4/CU). 4 waves: wave w ->
// row-tile t=w&1 (rows n0+t*16..+15), key-half kh2=w>>1 (cols kh2*32 of each
// 64-key step; cm in {kh2*2, kh2*2+1}). 32 steps, K-tiles 3-deep staged LDS.
// l combined across key-half wave-pairs in LDS at block end.
__global__ __launch_bounds__(256, 4) void pass1_kernel(
    const float* __restrict__ queries, const unsigned short* __restrict__ Atlg,
    const float* __restrict__ vhg, const unsigned short* __restrict__ Kb,
    unsigned short* __restrict__ Qhs, float* __restrict__ u_ws) {
    const int h = blockIdx.y;
    const int n0 = blockIdx.x * 32;
    const int tid = threadIdx.x;
    const int w = tid >> 6, lane = tid & 63;
    const int ln = lane & 15, quad = lane >> 4;
    const int t = w & 1, kh2 = w >> 1;

    __shared__ __align__(16) unsigned char lds[29440];
    __shared__ float vhs[64];
    // phase A: qstage @0 ([32][72]*2B=4608), Atl @4608 (9216, ends 13824)
    // loop:    Kbuf[3] @0/@8192/@16384 (SWZ [64][64]), qh @24576 ([32][72])
    // epilogue: lsum @29184 ([2][32] f32)
    unsigned short* qstage = (unsigned short*)lds;
    unsigned short* Atl = (unsigned short*)(lds + 4608);
    unsigned short* qh = (unsigned short*)(lds + 24576);
    float* lsum = (float*)(lds + 29184);

    // ---- phase A: stage queries (bf16), Atl (coalesced), vhs ---------------
    {
        int row = tid >> 3, c8 = (tid & 7) * 8;
        const float* qp = queries + (size_t)(n0 + row) * 64 + c8;
        float4 a = *(const float4*)qp;
        float4 b = *(const float4*)(qp + 4);
        *(ushort4*)&qstage[row * 72 + c8] =
            (ushort4){f2bf(a.x), f2bf(a.y), f2bf(a.z), f2bf(a.w)};
        *(ushort4*)&qstage[row * 72 + c8 + 4] =
            (ushort4){f2bf(b.x), f2bf(b.y), f2bf(b.z), f2bf(b.w)};
    }
    #pragma unroll
    for (int k = 0; k < 2; ++k) {
        int seg = tid * 2 + k, row = seg >> 3, off = (seg & 7) * 8;
        *(shortx8*)&Atl[row * 72 + off] =
            *(const shortx8*)&Atlg[h * 4096 + row * 64 + off];
    }
    if (tid < 64) vhs[tid] = vhg[h * 64 + tid];
    __syncthreads();

    // ---- phase B: qhat; wave (t, kh2) -> row-tile t, cn in {kh2*2,kh2*2+1} -
    {
        shortx8 qa[2];
        #pragma unroll
        for (int kk = 0; kk < 2; ++kk)
            qa[kk] = *(shortx8*)&qstage[(t * 16 + ln) * 72 + kk * 32 + quad * 8];
        #pragma unroll
        for (int i = 0; i < 2; ++i) {
            int cn = kh2 * 2 + i;
            floatx4 acc = {};
            #pragma unroll
            for (int kk = 0; kk < 2; ++kk) {
                shortx8 bfr = *(shortx8*)&Atl[(cn * 16 + ln) * 72 + kk * 32 + quad * 8];
                acc = __builtin_amdgcn_mfma_f32_16x16x32_bf16(qa[kk], bfr, acc, 0, 0, 0);
            }
            #pragma unroll
            for (int r = 0; r < 4; ++r)
                qh[(t * 16 + quad * 4 + r) * 72 + cn * 16 + ln] =
                    f2bf((acc[r] + vhs[cn * 16 + ln]) * QSCALE);
        }
    }
    __syncthreads();   // qh published; qstage/Atl dead

    // ---- prologue: Qhs copy (32 rows); stage s0; preload s1; qf ------------
    {
        int row = tid >> 3, off = (tid & 7) * 8;
        *(shortx8*)&Qhs[((size_t)h * 2048 + n0 + row) * 64 + off] =
            *(shortx8*)&qh[row * 72 + off];
    }
    const int srow = tid >> 2, sc = (tid & 3) * 16;
    #pragma unroll
    for (int i = 0; i < 2; ++i)
        *(shortx8*)(lds + SWZ(srow, sc * 2 + i * 16)) =
            *(const shortx8*)&Kb[(size_t)srow * 64 + sc + i * 8];
    shortx8 kr[2];
    #pragma unroll
    for (int i = 0; i < 2; ++i)
        kr[i] = *(const shortx8*)&Kb[(size_t)(64 + srow) * 64 + sc + i * 8];
    shortx8 qf[2];
    #pragma unroll
    for (int kk = 0; kk < 2; ++kk)
        qf[kk] = *(shortx8*)&qh[(t * 16 + ln) * 72 + kk * 32 + quad * 8];
    __syncthreads();

    // ---- main loop: 32 steps of 64 keys, 3-deep staging --------------------
    float lacc[4] = {};
    int rb = 0;
    for (int s = 0; s < 32; ++s) {
        const unsigned char* kb = lds + rb * 8192;
        const int wb = (rb == 2) ? 0 : rb + 1;
        if (s < 31) {          // publish tile s+1 (buf last read at step s-2)
            #pragma unroll
            for (int i = 0; i < 2; ++i)
                *(shortx8*)(lds + wb * 8192 + SWZ(srow, sc * 2 + i * 16)) = kr[i];
        }
        if (s < 30) {          // issue tile s+2
            int m0n = (s + 2) * 64;
            #pragma unroll
            for (int i = 0; i < 2; ++i)
                kr[i] = *(const shortx8*)&Kb[(size_t)(m0n + srow) * 64 + sc + i * 8];
        }
        #pragma unroll
        for (int i = 0; i < 2; ++i) {
            int cm = kh2 * 2 + i;
            shortx8 kf0 = *(const shortx8*)(kb + SWZ(cm * 16 + ln, quad * 16));
            shortx8 kf1 = *(const shortx8*)(kb + SWZ(cm * 16 + ln, 64 + quad * 16));
            floatx4 acc = {};
            acc = __builtin_amdgcn_mfma_f32_16x16x32_bf16(qf[0], kf0, acc, 0, 0, 0);
            acc = __builtin_amdgcn_mfma_f32_16x16x32_bf16(qf[1], kf1, acc, 0, 0, 0);
            #pragma unroll
            for (int r = 0; r < 4; ++r)
                lacc[r] += __builtin_amdgcn_exp2f(acc[r]);
        }
        __syncthreads();
        rb = wb;
    }

    // ---- epilogue: key-half partial row sums, combine, write u = 1/l -------
    #pragma unroll
    for (int r = 0; r < 4; ++r) {
        float x = lacc[r];
        #pragma unroll
        for (int o = 1; o <= 8; o <<= 1) x += __shfl_xor(x, o);
        if (ln == 0) lsum[kh2 * 32 + t * 16 + quad * 4 + r] = x;
    }
    __syncthreads();
    if (tid < 32)
        u_ws[(size_t)h * 2048 + n0 + tid] = 1.0f / (lsum[tid] + lsum[32 + tid]);
}

// =================== pass2: g[h,m]=sum_n exp2(qhat.k)*u[n]; fold r ==========
// grid (64 mtiles of 32 cols, 16 h) = 1024 blocks (4/CU). 4 waves: wave w ->
// col-tile t=w&1 (cols mb+t*16, kf resident), row-half rh=w>>1 (rows rh*32 of
// each 64-row step; rt in {rh*2, rh*2+1}). Qhs-tiles 3-deep staged LDS (+u).
// g combined across row-half wave-pairs in LDS; fold r = g.values, atomicAdd.
__global__ __launch_bounds__(256, 4) void pass2_kernel(
    const unsigned short* __restrict__ Qhs, const float* __restrict__ u_ws,
    const unsigned short* __restrict__ Kb, const float* __restrict__ values,
    float* __restrict__ r_ws) {
    const int h = blockIdx.y;
    const int mb = blockIdx.x * 32;
    const int tid = threadIdx.x;
    const int w = tid >> 6, lane = tid & 63;
    const int ln = lane & 15, quad = lane >> 4;
    const int t = w & 1, rh = w >> 1;

    __shared__ __align__(16) unsigned char lds[26624];
    // Qbuf[3] @0..24576 (SWZ [64][64]); u_sb[3][64] f32 @24576 (768);
    // g_part[2][32] @25344 (256); Rred[4][64] @25600 (1024, ends 26624)
    float* u_sb = (float*)(lds + 24576);
    float* g_part = (float*)(lds + 25344);
    float* Rred = (float*)(lds + 25600);

    // K frags for this wave's 16 columns (resident)
    shortx8 kf[2];
    #pragma unroll
    for (int kk = 0; kk < 2; ++kk)
        kf[kk] = *(const shortx8*)&Kb[(size_t)(mb + t * 16 + ln) * 64 + kk * 32 + quad * 8];

    // stage s0 (q-rows 0..63) + u0; preload s1 regs
    const int srow = tid >> 2, sc = (tid & 3) * 16;
    #pragma unroll
    for (int i = 0; i < 2; ++i)
        *(shortx8*)(lds + SWZ(srow, sc * 2 + i * 16)) =
            *(const shortx8*)&Qhs[((size_t)h * 2048 + srow) * 64 + sc + i * 8];
    if (tid < 64) u_sb[tid] = u_ws[(size_t)h * 2048 + tid];
    shortx8 qrn[2];
    float urn = 0.f;
    #pragma unroll
    for (int i = 0; i < 2; ++i)
        qrn[i] = *(const shortx8*)&Qhs[((size_t)h * 2048 + 64 + srow) * 64 + sc + i * 8];
    if (tid < 64) urn = u_ws[(size_t)h * 2048 + 64 + tid];
    __syncthreads();

    // ---- main loop: 32 steps of 64 q-rows, 3-deep staging ------------------
    float gacc = 0.f;
    int rb = 0;
    for (int s = 0; s < 32; ++s) {
        const unsigned char* qb = lds + rb * 8192;
        const float* us = u_sb + rb * 64;
        const int wb = (rb == 2) ? 0 : rb + 1;
        if (s < 31) {          // publish tile s+1
            #pragma unroll
            for (int i = 0; i < 2; ++i)
                *(shortx8*)(lds + wb * 8192 + SWZ(srow, sc * 2 + i * 16)) = qrn[i];
            if (tid < 64) u_sb[wb * 64 + tid] = urn;
        }
        if (s < 30) {          // issue tile s+2
            int n0n = (s + 2) * 64;
            #pragma unroll
            for (int i = 0; i < 2; ++i)
                qrn[i] = *(const shortx8*)&Qhs[((size_t)h * 2048 + n0n + srow) * 64 + sc + i * 8];
            if (tid < 64) urn = u_ws[(size_t)h * 2048 + n0n + tid];
        }
        #pragma unroll
        for (int i = 0; i < 2; ++i) {
            int rt = rh * 2 + i;
            shortx8 qa0 = *(const shortx8*)(qb + SWZ(rt * 16 + ln, quad * 16));
            shortx8 qa1 = *(const shortx8*)(qb + SWZ(rt * 16 + ln, 64 + quad * 16));
            floatx4 acc = {};
            acc = __builtin_amdgcn_mfma_f32_16x16x32_bf16(qa0, kf[0], acc, 0, 0, 0);
            acc = __builtin_amdgcn_mfma_f32_16x16x32_bf16(qa1, kf[1], acc, 0, 0, 0);
            #pragma unroll
            for (int r = 0; r < 4; ++r)
                gacc += __builtin_amdgcn_exp2f(acc[r]) * us[rt * 16 + quad * 4 + r];
        }
        __syncthreads();
        rb = wb;
    }

    // ---- combine row-half partials, fold r_part = g . values ---------------
    gacc += __shfl_xor(gacc, 16);
    gacc += __shfl_xor(gacc, 32);
    if (quad == 0) g_part[rh * 32 + t * 16 + ln] = gacc;  // col mb + t*16 + ln
    __syncthreads();
    {
        int grp = tid >> 6, v = tid & 63;
        float acc = 0.f;
        #pragma unroll
        for (int j = 0; j < 8; ++j) {
            float gs = g_part[grp * 8 + j] + g_part[32 + grp * 8 + j];
            acc += gs * values[(size_t)(mb + grp * 8 + j) * 64 + v];
        }
        Rred[grp * 64 + v] = acc;
    }
    __syncthreads();
    if (tid < 64)
        atomicAdd(&r_ws[h * 64 + tid],
                  Rred[tid] + Rred[64 + tid] + Rred[128 + tid] + Rred[192 + tid]);
}

// =================== pool: pooled[d] = 2048*sum_h bv + sum_hv r*Wv ----------
__global__ __launch_bounds__(256) void pool_kernel(
    const float* __restrict__ Wv, const float* __restrict__ bv,
    const float* __restrict__ r_ws, float* __restrict__ pooled) {
    const int tid = threadIdx.x;
    const int d0 = blockIdx.x * 16;       // grid 64
    const int d = tid & 15, hh = tid >> 4;
    __shared__ float red[16][17];
    float acc = bv[hh * 1024 + d0 + d] * 2048.0f;
    const float* rv = r_ws + hh * 64;
    const float* wp = Wv + (size_t)hh * 64 * 1024 + d0 + d;
    #pragma unroll 8
    for (int v = 0; v < 64; ++v) acc += rv[v] * wp[(size_t)v * 1024];
    red[hh][d] = acc;
    __syncthreads();
    if (tid < 16) {
        float s = 0.f;
        #pragma unroll
        for (int g = 0; g < 16; ++g) s += red[g][tid];
        pooled[d0 + tid] = s;
    }
}

// =================== out: out[dp] = pooled . Wo[dp,:] + bo[dp] ---------------
__global__ __launch_bounds__(256) void out_kernel(
    const float* __restrict__ Wo, const float* __restrict__ bo,
    const float* __restrict__ pooled, float* __restrict__ out) {
    const int tid = threadIdx.x, w = tid >> 6, lane = tid & 63;
    const int dp = blockIdx.x * 4 + w;    // grid 256
    const float* wr = Wo + (size_t)dp * 1024 + lane * 16;
    const float* pp = pooled + lane * 16;
    float acc = 0.f;
    #pragma unroll
    for (int u = 0; u < 4; ++u) {
        float4 a = *(const float4*)&wr[u * 4];
        float4 p = *(const float4*)&pp[u * 4];
        acc += a.x * p.x + a.y * p.y + a.z * p.z + a.w * p.w;
    }
    #pragma unroll
    for (int o = 32; o > 0; o >>= 1) acc += __shfl_xor(acc, o);
    if (lane == 0) out[dp] = acc + bo[dp];
}

extern "C" void kernel_launch(void* const* d_in, const int* in_sizes, int n_in,
                              void* d_out, int out_size, void* d_ws, size_t ws_size,
                              hipStream_t stream) {
    const float* queries = (const float*)d_in[0];
    const float* keys    = (const float*)d_in[1];
    const float* values  = (const float*)d_in[2];
    const float* Wq      = (const float*)d_in[3];
    const float* bq      = (const float*)d_in[4];
    const float* Wk      = (const float*)d_in[5];
    // d_in[6] = bk: row-constant under softmax, unused
    const float* Wv      = (const float*)d_in[7];
    const float* bv      = (const float*)d_in[8];
    const float* Wo      = (const float*)d_in[9];
    const float* bo      = (const float*)d_in[10];
    float* out = (float*)d_out;

    // workspace layout (bytes). Qhs (4MB) overlays Apart+vhpart: Apart/vhpart
    // are dead after reduceA, and pass1 (which writes Qhs) launches after it.
    char* base = (char*)d_ws;
    unsigned short* Qhs = (unsigned short*)base;             // 16*2048*64 bf16 = 4MB
    float* Apart  = (float*)base;                            // 128*4096 f (overlay)
    float* vhpart = Apart + 524288;                          // 128*64 f (overlay)
    float* u_ws   = (float*)(base + 4194304);                // 16*2048 f
    float* r_ws   = (float*)(base + 4325376);                // 1024 f
    float* pooled = (float*)(base + 4329472);                // 1024 f
    unsigned short* Kb   = (unsigned short*)(base + 4333568);  // 2048*64 bf16
    unsigned short* Atlg = (unsigned short*)(base + 4595712);  // 16*64*64 bf16
    float* vhg    = (float*)(base + 4726784);                // 16*64 f
    // total ws: ~4.52 MB

    prep_kernel<<<144, 256, 0, stream>>>(Wq, Wk, bq, keys,
                                         Apart, vhpart, Kb, r_ws);
    reduceA_kernel<<<64, 256, 0, stream>>>(Apart, vhpart, Atlg, vhg);
    pass1_kernel<<<dim3(64, 16), 256, 0, stream>>>(queries, Atlg, vhg,
                                                   Kb, Qhs, u_ws);
    pass2_kernel<<<dim3(64, 16), 256, 0, stream>>>(Qhs, u_ws, Kb, values, r_ws);
    pool_kernel<<<64, 256, 0, stream>>>(Wv, bv, r_ws, pooled);
    out_kernel<<<256, 256, 0, stream>>>(Wo, bo, pooled, out);
}